// Round 14
// baseline (82.397 us; speedup 1.0000x reference)
//
#include <hip/hip_runtime.h>
#include <math.h>

// B=4, N=8, T=512, D=256, H=8, DK=32. BN=32, ROWS=16384.
// R14: proj GEMM re-tiled to 64M x 256N (full-N) -> each fp32 A row fetched
// ONCE from HBM (was 2x). Same single-buf 2-barrier schedule, 48KB LDS,
// 3 blocks/CU, identical per-element accumulation order as R13.
// prep / attn / outproj unchanged from R13.

typedef __attribute__((ext_vector_type(8))) short bf16x8;
typedef __attribute__((ext_vector_type(4))) float f32x4;
typedef __attribute__((ext_vector_type(16))) float f32x16;
typedef __attribute__((ext_vector_type(4))) int i32x4;

__device__ __forceinline__ unsigned short f2bf(float f) {
    unsigned u = __float_as_uint(f);
    return (unsigned short)((u + 0x7fff + ((u >> 16) & 1)) >> 16);
}
__device__ __forceinline__ float ex2(float x) {
    float r; asm("v_exp_f32 %0, %1" : "=v"(r) : "v"(x)); return r;
}
__device__ __forceinline__ int cvtpk(float lo, float hi) {
    int r; asm("v_cvt_pk_bf16_f32 %0, %1, %2" : "=v"(r) : "v"(lo), "v"(hi)); return r;
}
__device__ __forceinline__ void gll16(const void* gsrc, const void* ldst) {
    __builtin_amdgcn_global_load_lds(
        (const __attribute__((address_space(1))) unsigned int*)gsrc,
        (__attribute__((address_space(3))) unsigned int*)ldst, 16, 0, 0);
}

// scale(1/sqrt(32)) * log2(e): folded into Q projection -> softmax in exp2 domain
#define SCL (0.17677669529663689f * 1.4426950408889634f)

// ---- workspace byte offsets ----
#define OFF_ZERO 0u           // 64 f32 zero-page for im2col edge rows
#define OFF_BTQ  25231360u    // 256*768 bf16
#define OFF_BTK  25624576u
#define OFF_BEFF 26017792u    // 2*256 f32
#define OFF_WVT  26019840u    // 256*256 bf16
#define OFF_WOT  26150912u    // 256*256 bf16
#define OFF_QB   26413056u    // 16384*256 bf16
#define OFF_KB   34801664u
#define OFF_VV   43190272u
#define OFF_CTX  51578880u

// ---------------- weight prep (folded conv mats, transposes, biases, zero-page) ----------------
__global__ __launch_bounds__(256) void prep(
    const float* __restrict__ Wq, const float* __restrict__ Wk,
    const float* __restrict__ bq, const float* __restrict__ bk,
    const float* __restrict__ wp, const float* __restrict__ wv,
    const float* __restrict__ wa, const float* __restrict__ b_pos,
    const float* __restrict__ Wv, const float* __restrict__ Wo,
    unsigned short* __restrict__ BtQ, unsigned short* __restrict__ BtK,
    float* __restrict__ beff, unsigned short* __restrict__ WVT,
    unsigned short* __restrict__ WOT, float* __restrict__ zeropage)
{
    int bid = blockIdx.x;
    if (bid < 1536) {                       // folded conv mats (Q side pre-scaled)
        int idx = bid * 256 + threadIdx.x;  // 2*3*256*256
        int which = idx / 196608;
        int r = idx - which * 196608;
        int j = r >> 16;
        int rem = r & 65535;
        int n = rem >> 8;
        int d = rem & 255;
        const float* W = which ? Wk : Wq;
        float val = wp[d * 3 + j] * W[d * 256 + n]
                  + wv[d * 3 + j] * W[(256 + d) * 256 + n]
                  + wa[d * 3 + j] * W[(512 + d) * 256 + n];
        if (!which) val *= SCL;
        (which ? BtK : BtQ)[n * 768 + j * 256 + d] = f2bf(val);
    } else if (bid < 2048) {                // Wv / Wo transposes (bf16)
        int idx = (bid - 1536) * 256 + threadIdx.x;   // 2*65536
        int which = idx >> 16;
        int r = idx & 65535;
        int n = r >> 8, kk = r & 255;
        if (!which) WVT[n * 256 + kk] = f2bf(Wv[kk * 256 + n]);
        else        WOT[n * 256 + kk] = f2bf(Wo[kk * 256 + n]);
    } else if (bid < 2050) {                // effective biases
        int which = bid - 2048;
        int n = threadIdx.x;
        const float* W = which ? Wk : Wq;
        const float* bb = which ? bk : bq;
        float s = bb[n];
        for (int d = 0; d < 256; ++d) s = fmaf(b_pos[d], W[d * 256 + n], s);
        if (!which) s *= SCL;
        beff[which * 256 + n] = s;
    } else {                                // zero-page (64 floats)
        if (threadIdx.x < 64) zeropage[threadIdx.x] = 0.f;
    }
}

// ---------------- fp32-A GEMM: 64M x 256N (full N), BK=64, single-buf, 2 barriers ----------------
// A fp32 read directly (IM2COL: k = tap*256 + channel, edge rows -> zero-page).
// B bf16 [256 n][KTOT k]. A LDS rows = 64 f32 (16 chunks x 16B), phys chunk p
// at row r holds logical p^(r&15); B rows = 64 bf16 (8 chunks), phys p^(r&7).
// bf16 conversion at fragment time via v_cvt_pk (RNE).
// 4 waves, each 32M x 128N (wm = wid>>1, wn = wid&1).
template<int KTOT, bool IM2COL>
__device__ __forceinline__ void gemmf32(
    const float* __restrict__ A, const unsigned short* __restrict__ Bt,
    const float* __restrict__ bias, const float* __restrict__ zeropage,
    unsigned short* __restrict__ Out, float* Asf, unsigned short* Bs)
{
    const int tid = threadIdx.x;
    const int wid = tid >> 6, l = tid & 63;
    const int l31 = l & 31, h2 = l >> 5;
    const int wm = wid >> 1, wn = wid & 1;
    const int m0 = blockIdx.x * 64;

    f32x16 acc[4] = {};

    for (int k0 = 0; k0 < KTOT; k0 += 64) {
        __syncthreads();
        // ---- stage A fp32: 64 rows x 16 chunks = 1024 chunks (4 per thread) ----
        #pragma unroll
        for (int q = 0; q < 4; ++q) {
            int cidx = q * 256 + tid;
            int row = cidx >> 4, cch = cidx & 15;
            int csrc = (cch ^ (row & 15)) * 4;          // float offset in 64-wide slice
            const float* asrc;
            if constexpr (IM2COL) {
                int seq = m0 >> 9, t0 = m0 & 511;
                int st = t0 + row + (k0 >> 8) - 1;
                asrc = (st >= 0 && st < 512)
                     ? A + ((size_t)(seq * 512 + st) * 256 + (k0 & 255) + csrc)
                     : zeropage + csrc;
            } else {
                asrc = A + ((size_t)(m0 + row) * 256 + k0 + csrc);
            }
            gll16(asrc, Asf + (size_t)cidx * 4);
        }
        // ---- stage B bf16: 256 rows x 8 chunks = 2048 chunks (8 per thread) ----
        #pragma unroll
        for (int q = 0; q < 8; ++q) {
            int cidx = q * 256 + tid;
            int row = cidx >> 3, c = cidx & 7;
            gll16(Bt + (size_t)row * KTOT + k0 + ((c ^ (row & 7)) * 8),
                  Bs + (size_t)cidx * 8);
        }
        __syncthreads();
        #pragma unroll
        for (int ks = 0; ks < 4; ++ks) {
            const int c = ks * 2 + h2;                  // logical 8-elem chunk 0..7
            // A fragment (32 rows of this wave's M-strip)
            const int r = wm * 32 + l31;
            f32x4 f0 = *(const f32x4*)&Asf[r * 64 + (((2 * c) ^ (r & 15)) * 4)];
            f32x4 f1 = *(const f32x4*)&Asf[r * 64 + (((2 * c + 1) ^ (r & 15)) * 4)];
            i32x4 w = {cvtpk(f0[0], f0[1]), cvtpk(f0[2], f0[3]),
                       cvtpk(f1[0], f1[1]), cvtpk(f1[2], f1[3])};
            bf16x8 af = __builtin_bit_cast(bf16x8, w);
            #pragma unroll
            for (int nt = 0; nt < 4; ++nt) {
                int rn = wn * 128 + nt * 32 + l31;
                bf16x8 bfr = *(const bf16x8*)&Bs[rn * 64 + ((c ^ (rn & 7)) * 8)];
                acc[nt] = __builtin_amdgcn_mfma_f32_32x32x16_bf16(af, bfr, acc[nt], 0, 0, 0);
            }
        }
    }

    // epilogue: C/D 32x32 layout: col = lane&31, row = (reg&3) + 8*(reg>>2) + 4*(lane>>5)
    #pragma unroll
    for (int nt = 0; nt < 4; ++nt) {
        const int col = wn * 128 + nt * 32 + l31;
        const float bb = bias[col];
        #pragma unroll
        for (int r = 0; r < 16; ++r) {
            const int row = m0 + wm * 32 + 4 * h2 + (r & 3) + 8 * (r >> 2);
            Out[(size_t)row * 256 + col] = f2bf(acc[nt][r] + bb);
        }
    }
}

// ---------------- bf16-A GEMM (outproj): 128M x 128N, BK=64 (R13 verbatim) ----------------
template<int KTOT, typename OutT>
__device__ __forceinline__ void gemm97(
    const unsigned short* __restrict__ A, const unsigned short* __restrict__ Bt,
    const float* __restrict__ bias, OutT* __restrict__ Out,
    unsigned short* As, unsigned short* Bs)
{
    const int tid = threadIdx.x;
    const int wid = tid >> 6, l = tid & 63;
    const int l31 = l & 31, h2 = l >> 5;
    const int wm = wid >> 1, wn = wid & 1;
    const int m0 = blockIdx.x * 128, n0 = blockIdx.y * 128;

    f32x16 acc[2][2] = {};

    for (int k0 = 0; k0 < KTOT; k0 += 64) {
        __syncthreads();
        #pragma unroll
        for (int q = 0; q < 4; ++q) {
            int cidx = q * 256 + tid;
            int row = cidx >> 3;
            int csrc = ((cidx & 7) ^ (row & 7)) * 8;
            gll16(A + (size_t)(m0 + row) * 256 + (k0 & 255) + csrc, As + (size_t)cidx * 8);
            gll16(Bt + (size_t)(n0 + row) * KTOT + k0 + csrc, Bs + (size_t)cidx * 8);
        }
        __syncthreads();
        #pragma unroll
        for (int ks = 0; ks < 4; ++ks) {
            bf16x8 af[2], bfr[2];
            #pragma unroll
            for (int mt = 0; mt < 2; ++mt) {
                int r = wm * 64 + mt * 32 + l31;
                af[mt] = *(const bf16x8*)&As[r * 64 + (((ks * 2 + h2) ^ (r & 7)) * 8)];
            }
            #pragma unroll
            for (int nt = 0; nt < 2; ++nt) {
                int rn = wn * 64 + nt * 32 + l31;
                bfr[nt] = *(const bf16x8*)&Bs[rn * 64 + (((ks * 2 + h2) ^ (rn & 7)) * 8)];
            }
            #pragma unroll
            for (int mt = 0; mt < 2; ++mt)
                #pragma unroll
                for (int nt = 0; nt < 2; ++nt)
                    acc[mt][nt] = __builtin_amdgcn_mfma_f32_32x32x16_bf16(af[mt], bfr[nt], acc[mt][nt], 0, 0, 0);
        }
    }

    #pragma unroll
    for (int nt = 0; nt < 2; ++nt) {
        const int col = n0 + wn * 64 + nt * 32 + l31;
        const float bb = bias[col];
        #pragma unroll
        for (int mt = 0; mt < 2; ++mt) {
            #pragma unroll
            for (int r = 0; r < 16; ++r) {
                const int row = m0 + wm * 64 + mt * 32 + 4 * h2 + (r & 3) + 8 * (r >> 2);
                float v = acc[mt][nt][r] + bb;
                if constexpr (sizeof(OutT) == 2) Out[(size_t)row * 256 + col] = (OutT)f2bf(v);
                else Out[(size_t)row * 256 + col] = v;
            }
        }
    }
}

// one launch: z=0 Q-proj, z=1 K-proj (fp32 im2col), z=2 V-proj (fp32 plain)
__global__ __launch_bounds__(256) void proj_fused(
    const float* __restrict__ query, const float* __restrict__ key,
    const float* __restrict__ value,
    const unsigned short* __restrict__ BTQ, const unsigned short* __restrict__ BTK,
    const unsigned short* __restrict__ WVT,
    const float* __restrict__ BEFF, const float* __restrict__ bv,
    const float* __restrict__ zeropage,
    unsigned short* __restrict__ QB, unsigned short* __restrict__ KB,
    unsigned short* __restrict__ VV)
{
    __shared__ alignas(16) float Asf[4096];             // 16 KB (64 rows x 64 f32)
    __shared__ alignas(16) unsigned short Bs[16384];    // 32 KB (256 rows x 64 bf16)
    const int z = blockIdx.z;
    if (z == 0)      gemmf32<768, true>(query, BTQ, BEFF, zeropage, QB, Asf, Bs);
    else if (z == 1) gemmf32<768, true>(key, BTK, BEFF + 256, zeropage, KB, Asf, Bs);
    else             gemmf32<256, false>(value, WVT, bv, zeropage, VV, Asf, Bs);
}

__global__ __launch_bounds__(256) void outproj(
    const unsigned short* __restrict__ CTX, const unsigned short* __restrict__ WOT,
    const float* __restrict__ bo, float* __restrict__ Out)
{
    __shared__ alignas(16) unsigned short As[8192];
    __shared__ alignas(16) unsigned short Bs[8192];
    gemm97<256, float>(CTX, WOT, bo, Out, As, Bs);
}

// ---------------- q-inner fused attention: 1 block per (bn,h), 8 waves (R13 verbatim) ----------------
__global__ __launch_bounds__(512) void attn_mfma(const unsigned short* __restrict__ Qb,
                                                 const unsigned short* __restrict__ Kb,
                                                 const unsigned short* __restrict__ Vv,
                                                 const int* __restrict__ mask,
                                                 unsigned short* __restrict__ ctx) {
    __shared__ alignas(16) unsigned short Qs[512 * 32];      // full Q head-slice
    __shared__ alignas(16) unsigned short Ks[2][128 * 32];   // chunk-xor (c ^ (row&3))
    __shared__ alignas(16) unsigned short VsT[2][32 * 136];  // [d][key], 17-chunk rows
    __shared__ float Mb[2][128];

    const int bnh = blockIdx.x;
    const int bn = bnh >> 3, h = bnh & 7;
    const int tid = threadIdx.x, wid = tid >> 6, l = tid & 63;
    const int g = l >> 4, r15 = l & 15;
    const unsigned short* Qg = Qb + (size_t)bn * 512 * 256 + h * 32;
    const unsigned short* Kg = Kb + (size_t)bn * 512 * 256 + h * 32;
    const unsigned short* Vg = Vv + (size_t)bn * 512 * 256 + h * 32;
    const int* mp = mask + bn * 512;
    const int srow = tid >> 2;                       // K staging row
    const int vkey = tid & 127, vd0 = (tid >> 7) * 8;

    auto stageK = [&](int k0, int b) {
        int csrc = (((tid & 3) ^ (srow & 3))) * 8;
        gll16(Kg + ((size_t)(k0 + srow)) * 256 + csrc, &Ks[b][wid * 512]);
    };

    // ---- prologue: full Q, K0, V0, Mb0 ----
    #pragma unroll
    for (int q = 0; q < 4; ++q) {
        int chunk = q * 512 + tid;
        int row = chunk >> 2, c = chunk & 3;
        gll16(Qg + (size_t)row * 256 + c * 8, Qs + (q * 512 + wid * 64) * 8);
    }
    stageK(0, 0);
    {
        i32x4 vr = *(const i32x4*)(const void*)(Vg + (size_t)vkey * 256 + vd0);
        #pragma unroll
        for (int i = 0; i < 4; ++i) {
            unsigned u = (unsigned)vr[i];
            VsT[0][(vd0 + 2 * i) * 136 + vkey] = (unsigned short)(u & 0xffff);
            VsT[0][(vd0 + 2 * i + 1) * 136 + vkey] = (unsigned short)(u >> 16);
        }
        if (tid < 128) Mb[0][tid] = (mp[tid] != 0) ? -1e9f : 0.f;
    }
    __syncthreads();

    bf16x8 bq[4];
    #pragma unroll
    for (int qt = 0; qt < 4; ++qt)
        bq[qt] = *(const bf16x8*)&Qs[(qt * 128 + wid * 16 + r15) * 32 + g * 8];

    float mrun[4], lrun[4];
    f32x4 accO[4][2] = {};
    #pragma unroll
    for (int qt = 0; qt < 4; ++qt) { mrun[qt] = -1e30f; lrun[qt] = 0.f; }

    for (int kt = 0; kt < 4; ++kt) {
        const int cur = kt & 1, nxt = cur ^ 1;
        const int k0n = kt * 128 + 128;

        i32x4 vr;
        int mraw = 0;
        if (kt < 3) {
            stageK(k0n, nxt);
            vr = *(const i32x4*)(const void*)(Vg + ((size_t)(k0n + vkey)) * 256 + vd0);
            if (tid < 128) mraw = mp[k0n + tid];
        }

        bf16x8 av[2][4];
        #pragma unroll
        for (int mt = 0; mt < 2; ++mt)
            #pragma unroll
            for (int s = 0; s < 4; ++s)
                av[mt][s] = *(const bf16x8*)&VsT[cur][(mt * 16 + r15) * 136 + 32 * s + 8 * g];

        #pragma unroll
        for (int qt = 0; qt < 4; ++qt) {
            float p[8][4];
            float rmax = -3e38f;
            __builtin_amdgcn_s_setprio(1);
            #pragma unroll
            for (int t2 = 0; t2 < 8; ++t2) {
                const int base = 32 * (t2 >> 1) + 4 * (t2 & 1);
                const int arow = base + 8 * (r15 >> 2) + (r15 & 3);
                bf16x8 ak = *(const bf16x8*)&Ks[cur][arow * 32 + ((g ^ (arow & 3)) * 8)];
                f32x4 cin = *(const f32x4*)&Mb[cur][base + 8 * g];
                f32x4 st = __builtin_amdgcn_mfma_f32_16x16x32_bf16(ak, bq[qt], cin, 0, 0, 0);
                #pragma unroll
                for (int r = 0; r < 4; ++r) p[t2][r] = st[r];
                rmax = fmaxf(rmax, fmaxf(fmaxf(st[0], st[1]), fmaxf(st[2], st[3])));
            }
            __builtin_amdgcn_s_setprio(0);
            rmax = fmaxf(rmax, __shfl_xor(rmax, 16, 64));
            rmax = fmaxf(rmax, __shfl_xor(rmax, 32, 64));

            if (__ballot(rmax > mrun[qt])) {
                float mnew = fmaxf(mrun[qt], rmax);
                float fs = ex2(mrun[qt] - mnew);
                lrun[qt] *= fs;
                accO[qt][0] *= fs;
                accO[qt][1] *= fs;
                mrun[qt] = mnew;
            }
            float psum = 0.f;
            #pragma unroll
            for (int t2 = 0; t2 < 8; ++t2)
                #pragma unroll
                for (int r = 0; r < 4; ++r) {
                    float e = ex2(p[t2][r] - mrun[qt]);
                    p[t2][r] = e;
                    psum += e;
                }
            psum += __shfl_xor(psum, 16, 64);
            psum += __shfl_xor(psum, 32, 64);
            lrun[qt] += psum;

            bf16x8 pb[4];
            #pragma unroll
            for (int s = 0; s < 4; ++s) {
                i32x4 bi = {cvtpk(p[2 * s][0], p[2 * s][1]), cvtpk(p[2 * s][2], p[2 * s][3]),
                            cvtpk(p[2 * s + 1][0], p[2 * s + 1][1]), cvtpk(p[2 * s + 1][2], p[2 * s + 1][3])};
                pb[s] = __builtin_bit_cast(bf16x8, bi);
            }

            __builtin_amdgcn_s_setprio(1);
            #pragma unroll
            for (int mt = 0; mt < 2; ++mt)
                #pragma unroll
                for (int s = 0; s < 4; ++s)
                    accO[qt][mt] = __builtin_amdgcn_mfma_f32_16x16x32_bf16(av[mt][s], pb[s], accO[qt][mt], 0, 0, 0);
            __builtin_amdgcn_s_setprio(0);
        }

        if (kt < 3) {
            #pragma unroll
            for (int i = 0; i < 4; ++i) {
                unsigned u = (unsigned)vr[i];
                VsT[nxt][(vd0 + 2 * i) * 136 + vkey] = (unsigned short)(u & 0xffff);
                VsT[nxt][(vd0 + 2 * i + 1) * 136 + vkey] = (unsigned short)(u >> 16);
            }
            if (tid < 128) Mb[nxt][tid] = (mraw != 0) ? -1e9f : 0.f;
        }
        __syncthreads();
    }

    #pragma unroll
    for (int qt = 0; qt < 4; ++qt) {
        const float inv = 1.f / lrun[qt];
        const size_t orow = (size_t)bn * 512 + qt * 128 + wid * 16 + r15;
        #pragma unroll
        for (int mt = 0; mt < 2; ++mt) {
            ushort4 o;
            o.x = f2bf(accO[qt][mt][0] * inv);
            o.y = f2bf(accO[qt][mt][1] * inv);
            o.z = f2bf(accO[qt][mt][2] * inv);
            o.w = f2bf(accO[qt][mt][3] * inv);
            *(ushort4*)&ctx[orow * 256 + h * 32 + mt * 16 + 4 * g] = o;
        }
    }
}

extern "C" void kernel_launch(void* const* d_in, const int* in_sizes, int n_in,
                              void* d_out, int out_size, void* d_ws, size_t ws_size,
                              hipStream_t stream) {
    const float* query = (const float*)d_in[0];
    const float* key   = (const float*)d_in[1];
    const float* value = (const float*)d_in[2];
    const int*   kpm   = (const int*)d_in[3];
    const float* w_pos = (const float*)d_in[4];
    const float* b_pos = (const float*)d_in[5];
    const float* w_vel = (const float*)d_in[6];
    const float* w_acc = (const float*)d_in[7];
    const float* Wq    = (const float*)d_in[8];
    const float* bq    = (const float*)d_in[9];
    const float* Wk    = (const float*)d_in[10];
    const float* bk    = (const float*)d_in[11];
    const float* Wv    = (const float*)d_in[12];
    const float* bv    = (const float*)d_in[13];
    const float* Wo    = (const float*)d_in[14];
    const float* bo    = (const float*)d_in[15];

    unsigned char* w = (unsigned char*)d_ws;
    float*          ZP  = (float*)(w + OFF_ZERO);
    unsigned short* BTQ = (unsigned short*)(w + OFF_BTQ);
    unsigned short* BTK = (unsigned short*)(w + OFF_BTK);
    float*          BEFF= (float*)(w + OFF_BEFF);
    unsigned short* WVT = (unsigned short*)(w + OFF_WVT);
    unsigned short* WOT = (unsigned short*)(w + OFF_WOT);
    unsigned short* QB  = (unsigned short*)(w + OFF_QB);
    unsigned short* KB  = (unsigned short*)(w + OFF_KB);
    unsigned short* VV  = (unsigned short*)(w + OFF_VV);
    unsigned short* CTX = (unsigned short*)(w + OFF_CTX);

    prep<<<2051, 256, 0, stream>>>(Wq, Wk, bq, bk, w_pos, w_vel, w_acc, b_pos,
                                   Wv, Wo, BTQ, BTK, BEFF, WVT, WOT, ZP);

    proj_fused<<<dim3(256, 1, 3), 256, 0, stream>>>(query, key, value, BTQ, BTK, WVT,
                                                    BEFF, bv, ZP, QB, KB, VV);

    attn_mfma<<<256, 512, 0, stream>>>(QB, KB, VV, kpm, CTX);

    outproj<<<dim3(128, 2), 256, 0, stream>>>(CTX, WOT, bo, (float*)d_out);
}

// Round 15
// 80.539 us; speedup vs baseline: 1.0231x; 1.0231x over previous
//
#include <hip/hip_runtime.h>
#include <math.h>

// B=4, N=8, T=512, D=256, H=8, DK=32. BN=32, ROWS=16384.
// R15: proj reverted to R13 (128x128, single-buf, 2-barrier, fp32-A direct
// gll16 + cvt-at-fragment). attn: Q loaded global->register directly (Qs LDS
// staging deleted). prep / outproj unchanged.

typedef __attribute__((ext_vector_type(8))) short bf16x8;
typedef __attribute__((ext_vector_type(4))) float f32x4;
typedef __attribute__((ext_vector_type(16))) float f32x16;
typedef __attribute__((ext_vector_type(4))) int i32x4;

__device__ __forceinline__ unsigned short f2bf(float f) {
    unsigned u = __float_as_uint(f);
    return (unsigned short)((u + 0x7fff + ((u >> 16) & 1)) >> 16);
}
__device__ __forceinline__ float ex2(float x) {
    float r; asm("v_exp_f32 %0, %1" : "=v"(r) : "v"(x)); return r;
}
__device__ __forceinline__ int cvtpk(float lo, float hi) {
    int r; asm("v_cvt_pk_bf16_f32 %0, %1, %2" : "=v"(r) : "v"(lo), "v"(hi)); return r;
}
__device__ __forceinline__ void gll16(const void* gsrc, const void* ldst) {
    __builtin_amdgcn_global_load_lds(
        (const __attribute__((address_space(1))) unsigned int*)gsrc,
        (__attribute__((address_space(3))) unsigned int*)ldst, 16, 0, 0);
}

// scale(1/sqrt(32)) * log2(e): folded into Q projection -> softmax in exp2 domain
#define SCL (0.17677669529663689f * 1.4426950408889634f)

// ---- workspace byte offsets ----
#define OFF_ZERO 0u           // 64 f32 zero-page for im2col edge rows
#define OFF_BTQ  25231360u    // 256*768 bf16
#define OFF_BTK  25624576u
#define OFF_BEFF 26017792u    // 2*256 f32
#define OFF_WVT  26019840u    // 256*256 bf16
#define OFF_WOT  26150912u    // 256*256 bf16
#define OFF_QB   26413056u    // 16384*256 bf16
#define OFF_KB   34801664u
#define OFF_VV   43190272u
#define OFF_CTX  51578880u

// ---------------- weight prep (folded conv mats, transposes, biases, zero-page) ----------------
__global__ __launch_bounds__(256) void prep(
    const float* __restrict__ Wq, const float* __restrict__ Wk,
    const float* __restrict__ bq, const float* __restrict__ bk,
    const float* __restrict__ wp, const float* __restrict__ wv,
    const float* __restrict__ wa, const float* __restrict__ b_pos,
    const float* __restrict__ Wv, const float* __restrict__ Wo,
    unsigned short* __restrict__ BtQ, unsigned short* __restrict__ BtK,
    float* __restrict__ beff, unsigned short* __restrict__ WVT,
    unsigned short* __restrict__ WOT, float* __restrict__ zeropage)
{
    int bid = blockIdx.x;
    if (bid < 1536) {                       // folded conv mats (Q side pre-scaled)
        int idx = bid * 256 + threadIdx.x;  // 2*3*256*256
        int which = idx / 196608;
        int r = idx - which * 196608;
        int j = r >> 16;
        int rem = r & 65535;
        int n = rem >> 8;
        int d = rem & 255;
        const float* W = which ? Wk : Wq;
        float val = wp[d * 3 + j] * W[d * 256 + n]
                  + wv[d * 3 + j] * W[(256 + d) * 256 + n]
                  + wa[d * 3 + j] * W[(512 + d) * 256 + n];
        if (!which) val *= SCL;
        (which ? BtK : BtQ)[n * 768 + j * 256 + d] = f2bf(val);
    } else if (bid < 2048) {                // Wv / Wo transposes (bf16)
        int idx = (bid - 1536) * 256 + threadIdx.x;   // 2*65536
        int which = idx >> 16;
        int r = idx & 65535;
        int n = r >> 8, kk = r & 255;
        if (!which) WVT[n * 256 + kk] = f2bf(Wv[kk * 256 + n]);
        else        WOT[n * 256 + kk] = f2bf(Wo[kk * 256 + n]);
    } else if (bid < 2050) {                // effective biases
        int which = bid - 2048;
        int n = threadIdx.x;
        const float* W = which ? Wk : Wq;
        const float* bb = which ? bk : bq;
        float s = bb[n];
        for (int d = 0; d < 256; ++d) s = fmaf(b_pos[d], W[d * 256 + n], s);
        if (!which) s *= SCL;
        beff[which * 256 + n] = s;
    } else {                                // zero-page (64 floats)
        if (threadIdx.x < 64) zeropage[threadIdx.x] = 0.f;
    }
}

// ---------------- fp32-A GEMM: 128M x 128N, BK=64, single-buf, 2 barriers (R13) ----------------
template<int KTOT, bool IM2COL>
__device__ __forceinline__ void gemmf32(
    const float* __restrict__ A, const unsigned short* __restrict__ Bt,
    const float* __restrict__ bias, const float* __restrict__ zeropage,
    unsigned short* __restrict__ Out, float* Asf, unsigned short* Bs)
{
    const int tid = threadIdx.x;
    const int wid = tid >> 6, l = tid & 63;
    const int l31 = l & 31, h2 = l >> 5;
    const int wm = wid >> 1, wn = wid & 1;
    const int m0 = blockIdx.x * 128, n0 = blockIdx.y * 128;

    f32x16 acc[2][2] = {};

    for (int k0 = 0; k0 < KTOT; k0 += 64) {
        __syncthreads();
        // ---- stage A fp32: 2048 chunks (8 per thread) ----
        #pragma unroll
        for (int q = 0; q < 8; ++q) {
            int cidx = q * 256 + tid;
            int row = cidx >> 4, cch = cidx & 15;
            int csrc = (cch ^ (row & 15)) * 4;          // float offset in 64-wide slice
            const float* asrc;
            if constexpr (IM2COL) {
                int seq = m0 >> 9, t0 = m0 & 511;
                int st = t0 + row + (k0 >> 8) - 1;
                asrc = (st >= 0 && st < 512)
                     ? A + ((size_t)(seq * 512 + st) * 256 + (k0 & 255) + csrc)
                     : zeropage + csrc;
            } else {
                asrc = A + ((size_t)(m0 + row) * 256 + k0 + csrc);
            }
            gll16(asrc, Asf + (size_t)cidx * 4);
        }
        // ---- stage B bf16: 1024 chunks (4 per thread) ----
        #pragma unroll
        for (int q = 0; q < 4; ++q) {
            int cidx = q * 256 + tid;
            int row = cidx >> 3, c = cidx & 7;
            gll16(Bt + (size_t)(n0 + row) * KTOT + k0 + ((c ^ (row & 7)) * 8),
                  Bs + cidx * 8);
        }
        __syncthreads();
        #pragma unroll
        for (int ks = 0; ks < 4; ++ks) {
            const int c = ks * 2 + h2;                  // logical 8-elem chunk 0..7
            bf16x8 af[2], bfr[2];
            #pragma unroll
            for (int mt = 0; mt < 2; ++mt) {
                int r = wm * 64 + mt * 32 + l31;
                f32x4 f0 = *(const f32x4*)&Asf[r * 64 + (((2 * c) ^ (r & 15)) * 4)];
                f32x4 f1 = *(const f32x4*)&Asf[r * 64 + (((2 * c + 1) ^ (r & 15)) * 4)];
                i32x4 w = {cvtpk(f0[0], f0[1]), cvtpk(f0[2], f0[3]),
                           cvtpk(f1[0], f1[1]), cvtpk(f1[2], f1[3])};
                af[mt] = __builtin_bit_cast(bf16x8, w);
            }
            #pragma unroll
            for (int nt = 0; nt < 2; ++nt) {
                int rn = wn * 64 + nt * 32 + l31;
                bfr[nt] = *(const bf16x8*)&Bs[rn * 64 + ((c ^ (rn & 7)) * 8)];
            }
            #pragma unroll
            for (int mt = 0; mt < 2; ++mt)
                #pragma unroll
                for (int nt = 0; nt < 2; ++nt)
                    acc[mt][nt] = __builtin_amdgcn_mfma_f32_32x32x16_bf16(af[mt], bfr[nt], acc[mt][nt], 0, 0, 0);
        }
    }

    // epilogue: C/D 32x32 layout: col = lane&31, row = (reg&3) + 8*(reg>>2) + 4*(lane>>5)
    #pragma unroll
    for (int nt = 0; nt < 2; ++nt) {
        const int col = n0 + wn * 64 + nt * 32 + l31;
        const float bb = bias[col];
        #pragma unroll
        for (int mt = 0; mt < 2; ++mt) {
            #pragma unroll
            for (int r = 0; r < 16; ++r) {
                const int row = m0 + wm * 64 + mt * 32 + 4 * h2 + (r & 3) + 8 * (r >> 2);
                Out[(size_t)row * 256 + col] = f2bf(acc[mt][nt][r] + bb);
            }
        }
    }
}

// ---------------- bf16-A GEMM (outproj): 128M x 128N, BK=64 (R13 verbatim) ----------------
template<int KTOT, typename OutT>
__device__ __forceinline__ void gemm97(
    const unsigned short* __restrict__ A, const unsigned short* __restrict__ Bt,
    const float* __restrict__ bias, OutT* __restrict__ Out,
    unsigned short* As, unsigned short* Bs)
{
    const int tid = threadIdx.x;
    const int wid = tid >> 6, l = tid & 63;
    const int l31 = l & 31, h2 = l >> 5;
    const int wm = wid >> 1, wn = wid & 1;
    const int m0 = blockIdx.x * 128, n0 = blockIdx.y * 128;

    f32x16 acc[2][2] = {};

    for (int k0 = 0; k0 < KTOT; k0 += 64) {
        __syncthreads();
        #pragma unroll
        for (int q = 0; q < 4; ++q) {
            int cidx = q * 256 + tid;
            int row = cidx >> 3;
            int csrc = ((cidx & 7) ^ (row & 7)) * 8;
            gll16(A + (size_t)(m0 + row) * 256 + (k0 & 255) + csrc, As + (size_t)cidx * 8);
            gll16(Bt + (size_t)(n0 + row) * KTOT + k0 + csrc, Bs + (size_t)cidx * 8);
        }
        __syncthreads();
        #pragma unroll
        for (int ks = 0; ks < 4; ++ks) {
            bf16x8 af[2], bfr[2];
            #pragma unroll
            for (int mt = 0; mt < 2; ++mt) {
                int r = wm * 64 + mt * 32 + l31;
                af[mt] = *(const bf16x8*)&As[r * 64 + (((ks * 2 + h2) ^ (r & 7)) * 8)];
            }
            #pragma unroll
            for (int nt = 0; nt < 2; ++nt) {
                int rn = wn * 64 + nt * 32 + l31;
                bfr[nt] = *(const bf16x8*)&Bs[rn * 64 + (((ks * 2 + h2) ^ (rn & 7)) * 8)];
            }
            #pragma unroll
            for (int mt = 0; mt < 2; ++mt)
                #pragma unroll
                for (int nt = 0; nt < 2; ++nt)
                    acc[mt][nt] = __builtin_amdgcn_mfma_f32_32x32x16_bf16(af[mt], bfr[nt], acc[mt][nt], 0, 0, 0);
        }
    }

    #pragma unroll
    for (int nt = 0; nt < 2; ++nt) {
        const int col = n0 + wn * 64 + nt * 32 + l31;
        const float bb = bias[col];
        #pragma unroll
        for (int mt = 0; mt < 2; ++mt) {
            #pragma unroll
            for (int r = 0; r < 16; ++r) {
                const int row = m0 + wm * 64 + mt * 32 + 4 * h2 + (r & 3) + 8 * (r >> 2);
                float v = acc[mt][nt][r] + bb;
                if constexpr (sizeof(OutT) == 2) Out[(size_t)row * 256 + col] = (OutT)f2bf(v);
                else Out[(size_t)row * 256 + col] = v;
            }
        }
    }
}

// one launch: z=0 Q-proj, z=1 K-proj (fp32 im2col), z=2 V-proj (fp32 plain)
__global__ __launch_bounds__(256) void proj_fused(
    const float* __restrict__ query, const float* __restrict__ key,
    const float* __restrict__ value,
    const unsigned short* __restrict__ BTQ, const unsigned short* __restrict__ BTK,
    const unsigned short* __restrict__ WVT,
    const float* __restrict__ BEFF, const float* __restrict__ bv,
    const float* __restrict__ zeropage,
    unsigned short* __restrict__ QB, unsigned short* __restrict__ KB,
    unsigned short* __restrict__ VV)
{
    __shared__ alignas(16) float Asf[8192];             // 32 KB
    __shared__ alignas(16) unsigned short Bs[8192];     // 16 KB
    const int z = blockIdx.z;
    if (z == 0)      gemmf32<768, true>(query, BTQ, BEFF, zeropage, QB, Asf, Bs);
    else if (z == 1) gemmf32<768, true>(key, BTK, BEFF + 256, zeropage, KB, Asf, Bs);
    else             gemmf32<256, false>(value, WVT, bv, zeropage, VV, Asf, Bs);
}

__global__ __launch_bounds__(256) void outproj(
    const unsigned short* __restrict__ CTX, const unsigned short* __restrict__ WOT,
    const float* __restrict__ bo, float* __restrict__ Out)
{
    __shared__ alignas(16) unsigned short As[8192];
    __shared__ alignas(16) unsigned short Bs[8192];
    gemm97<256, float>(CTX, WOT, bo, Out, As, Bs);
}

// ---------------- q-inner fused attention: 1 block per (bn,h), 8 waves ----------------
// Q fragments loaded DIRECTLY global->register (no Qs LDS staging).
__global__ __launch_bounds__(512) void attn_mfma(const unsigned short* __restrict__ Qb,
                                                 const unsigned short* __restrict__ Kb,
                                                 const unsigned short* __restrict__ Vv,
                                                 const int* __restrict__ mask,
                                                 unsigned short* __restrict__ ctx) {
    __shared__ alignas(16) unsigned short Ks[2][128 * 32];   // chunk-xor (c ^ (row&3))
    __shared__ alignas(16) unsigned short VsT[2][32 * 136];  // [d][key], 17-chunk rows
    __shared__ float Mb[2][128];

    const int bnh = blockIdx.x;
    const int bn = bnh >> 3, h = bnh & 7;
    const int tid = threadIdx.x, wid = tid >> 6, l = tid & 63;
    const int g = l >> 4, r15 = l & 15;
    const unsigned short* Qg = Qb + (size_t)bn * 512 * 256 + h * 32;
    const unsigned short* Kg = Kb + (size_t)bn * 512 * 256 + h * 32;
    const unsigned short* Vg = Vv + (size_t)bn * 512 * 256 + h * 32;
    const int* mp = mask + bn * 512;
    const int srow = tid >> 2;                       // K staging row
    const int vkey = tid & 127, vd0 = (tid >> 7) * 8;

    auto stageK = [&](int k0, int b) {
        int csrc = (((tid & 3) ^ (srow & 3))) * 8;
        gll16(Kg + ((size_t)(k0 + srow)) * 256 + csrc, &Ks[b][wid * 512]);
    };

    // ---- prologue: Q direct to regs; K0, V0, Mb0 staged ----
    bf16x8 bq[4];
    #pragma unroll
    for (int qt = 0; qt < 4; ++qt)
        bq[qt] = *(const bf16x8*)(const void*)(Qg + ((size_t)(qt * 128 + wid * 16 + r15)) * 256 + g * 8);

    stageK(0, 0);
    {
        i32x4 vr = *(const i32x4*)(const void*)(Vg + (size_t)vkey * 256 + vd0);
        #pragma unroll
        for (int i = 0; i < 4; ++i) {
            unsigned u = (unsigned)vr[i];
            VsT[0][(vd0 + 2 * i) * 136 + vkey] = (unsigned short)(u & 0xffff);
            VsT[0][(vd0 + 2 * i + 1) * 136 + vkey] = (unsigned short)(u >> 16);
        }
        if (tid < 128) Mb[0][tid] = (mp[tid] != 0) ? -1e9f : 0.f;
    }
    __syncthreads();

    float mrun[4], lrun[4];
    f32x4 accO[4][2] = {};
    #pragma unroll
    for (int qt = 0; qt < 4; ++qt) { mrun[qt] = -1e30f; lrun[qt] = 0.f; }

    for (int kt = 0; kt < 4; ++kt) {
        const int cur = kt & 1, nxt = cur ^ 1;
        const int k0n = kt * 128 + 128;

        i32x4 vr;
        int mraw = 0;
        if (kt < 3) {
            stageK(k0n, nxt);
            vr = *(const i32x4*)(const void*)(Vg + ((size_t)(k0n + vkey)) * 256 + vd0);
            if (tid < 128) mraw = mp[k0n + tid];
        }

        bf16x8 av[2][4];
        #pragma unroll
        for (int mt = 0; mt < 2; ++mt)
            #pragma unroll
            for (int s = 0; s < 4; ++s)
                av[mt][s] = *(const bf16x8*)&VsT[cur][(mt * 16 + r15) * 136 + 32 * s + 8 * g];

        #pragma unroll
        for (int qt = 0; qt < 4; ++qt) {
            float p[8][4];
            float rmax = -3e38f;
            __builtin_amdgcn_s_setprio(1);
            #pragma unroll
            for (int t2 = 0; t2 < 8; ++t2) {
                const int base = 32 * (t2 >> 1) + 4 * (t2 & 1);
                const int arow = base + 8 * (r15 >> 2) + (r15 & 3);
                bf16x8 ak = *(const bf16x8*)&Ks[cur][arow * 32 + ((g ^ (arow & 3)) * 8)];
                f32x4 cin = *(const f32x4*)&Mb[cur][base + 8 * g];
                f32x4 st = __builtin_amdgcn_mfma_f32_16x16x32_bf16(ak, bq[qt], cin, 0, 0, 0);
                #pragma unroll
                for (int r = 0; r < 4; ++r) p[t2][r] = st[r];
                rmax = fmaxf(rmax, fmaxf(fmaxf(st[0], st[1]), fmaxf(st[2], st[3])));
            }
            __builtin_amdgcn_s_setprio(0);
            rmax = fmaxf(rmax, __shfl_xor(rmax, 16, 64));
            rmax = fmaxf(rmax, __shfl_xor(rmax, 32, 64));

            if (__ballot(rmax > mrun[qt])) {
                float mnew = fmaxf(mrun[qt], rmax);
                float fs = ex2(mrun[qt] - mnew);
                lrun[qt] *= fs;
                accO[qt][0] *= fs;
                accO[qt][1] *= fs;
                mrun[qt] = mnew;
            }
            float psum = 0.f;
            #pragma unroll
            for (int t2 = 0; t2 < 8; ++t2)
                #pragma unroll
                for (int r = 0; r < 4; ++r) {
                    float e = ex2(p[t2][r] - mrun[qt]);
                    p[t2][r] = e;
                    psum += e;
                }
            psum += __shfl_xor(psum, 16, 64);
            psum += __shfl_xor(psum, 32, 64);
            lrun[qt] += psum;

            bf16x8 pb[4];
            #pragma unroll
            for (int s = 0; s < 4; ++s) {
                i32x4 bi = {cvtpk(p[2 * s][0], p[2 * s][1]), cvtpk(p[2 * s][2], p[2 * s][3]),
                            cvtpk(p[2 * s + 1][0], p[2 * s + 1][1]), cvtpk(p[2 * s + 1][2], p[2 * s + 1][3])};
                pb[s] = __builtin_bit_cast(bf16x8, bi);
            }

            __builtin_amdgcn_s_setprio(1);
            #pragma unroll
            for (int mt = 0; mt < 2; ++mt)
                #pragma unroll
                for (int s = 0; s < 4; ++s)
                    accO[qt][mt] = __builtin_amdgcn_mfma_f32_16x16x32_bf16(av[mt][s], pb[s], accO[qt][mt], 0, 0, 0);
            __builtin_amdgcn_s_setprio(0);
        }

        if (kt < 3) {
            #pragma unroll
            for (int i = 0; i < 4; ++i) {
                unsigned u = (unsigned)vr[i];
                VsT[nxt][(vd0 + 2 * i) * 136 + vkey] = (unsigned short)(u & 0xffff);
                VsT[nxt][(vd0 + 2 * i + 1) * 136 + vkey] = (unsigned short)(u >> 16);
            }
            if (tid < 128) Mb[nxt][tid] = (mraw != 0) ? -1e9f : 0.f;
        }
        __syncthreads();
    }

    #pragma unroll
    for (int qt = 0; qt < 4; ++qt) {
        const float inv = 1.f / lrun[qt];
        const size_t orow = (size_t)bn * 512 + qt * 128 + wid * 16 + r15;
        #pragma unroll
        for (int mt = 0; mt < 2; ++mt) {
            ushort4 o;
            o.x = f2bf(accO[qt][mt][0] * inv);
            o.y = f2bf(accO[qt][mt][1] * inv);
            o.z = f2bf(accO[qt][mt][2] * inv);
            o.w = f2bf(accO[qt][mt][3] * inv);
            *(ushort4*)&ctx[orow * 256 + h * 32 + mt * 16 + 4 * g] = o;
        }
    }
}

extern "C" void kernel_launch(void* const* d_in, const int* in_sizes, int n_in,
                              void* d_out, int out_size, void* d_ws, size_t ws_size,
                              hipStream_t stream) {
    const float* query = (const float*)d_in[0];
    const float* key   = (const float*)d_in[1];
    const float* value = (const float*)d_in[2];
    const int*   kpm   = (const int*)d_in[3];
    const float* w_pos = (const float*)d_in[4];
    const float* b_pos = (const float*)d_in[5];
    const float* w_vel = (const float*)d_in[6];
    const float* w_acc = (const float*)d_in[7];
    const float* Wq    = (const float*)d_in[8];
    const float* bq    = (const float*)d_in[9];
    const float* Wk    = (const float*)d_in[10];
    const float* bk    = (const float*)d_in[11];
    const float* Wv    = (const float*)d_in[12];
    const float* bv    = (const float*)d_in[13];
    const float* Wo    = (const float*)d_in[14];
    const float* bo    = (const float*)d_in[15];

    unsigned char* w = (unsigned char*)d_ws;
    float*          ZP  = (float*)(w + OFF_ZERO);
    unsigned short* BTQ = (unsigned short*)(w + OFF_BTQ);
    unsigned short* BTK = (unsigned short*)(w + OFF_BTK);
    float*          BEFF= (float*)(w + OFF_BEFF);
    unsigned short* WVT = (unsigned short*)(w + OFF_WVT);
    unsigned short* WOT = (unsigned short*)(w + OFF_WOT);
    unsigned short* QB  = (unsigned short*)(w + OFF_QB);
    unsigned short* KB  = (unsigned short*)(w + OFF_KB);
    unsigned short* VV  = (unsigned short*)(w + OFF_VV);
    unsigned short* CTX = (unsigned short*)(w + OFF_CTX);

    prep<<<2051, 256, 0, stream>>>(Wq, Wk, bq, bk, w_pos, w_vel, w_acc, b_pos,
                                   Wv, Wo, BTQ, BTK, BEFF, WVT, WOT, ZP);

    proj_fused<<<dim3(128, 2, 3), 256, 0, stream>>>(query, key, value, BTQ, BTK, WVT,
                                                    BEFF, bv, ZP, QB, KB, VV);

    attn_mfma<<<256, 512, 0, stream>>>(QB, KB, VV, kpm, CTX);

    outproj<<<dim3(128, 2), 256, 0, stream>>>(CTX, WOT, bo, (float*)d_out);
}

// Round 16
// 79.018 us; speedup vs baseline: 1.0428x; 1.0192x over previous
//
#include <hip/hip_runtime.h>
#include <math.h>

// B=4, N=8, T=512, D=256, H=8, DK=32. BN=32, ROWS=16384.
// R16: proj im2col restructured tap-INNER: stage 130-row fp32 A halo tile once
// per channel-block (A staging /3, barriers 24->16), B (16KB) double-buffered
// across taps. V-proj = same kernel TAPS=1. attn/outproj/prep = R15 verbatim.

typedef __attribute__((ext_vector_type(8))) short bf16x8;
typedef __attribute__((ext_vector_type(4))) float f32x4;
typedef __attribute__((ext_vector_type(16))) float f32x16;
typedef __attribute__((ext_vector_type(4))) int i32x4;

__device__ __forceinline__ unsigned short f2bf(float f) {
    unsigned u = __float_as_uint(f);
    return (unsigned short)((u + 0x7fff + ((u >> 16) & 1)) >> 16);
}
__device__ __forceinline__ float ex2(float x) {
    float r; asm("v_exp_f32 %0, %1" : "=v"(r) : "v"(x)); return r;
}
__device__ __forceinline__ int cvtpk(float lo, float hi) {
    int r; asm("v_cvt_pk_bf16_f32 %0, %1, %2" : "=v"(r) : "v"(lo), "v"(hi)); return r;
}
__device__ __forceinline__ void gll16(const void* gsrc, const void* ldst) {
    __builtin_amdgcn_global_load_lds(
        (const __attribute__((address_space(1))) unsigned int*)gsrc,
        (__attribute__((address_space(3))) unsigned int*)ldst, 16, 0, 0);
}

// scale(1/sqrt(32)) * log2(e): folded into Q projection -> softmax in exp2 domain
#define SCL (0.17677669529663689f * 1.4426950408889634f)

// ---- workspace byte offsets ----
#define OFF_ZERO 0u           // 64 f32 zero-page for im2col edge rows
#define OFF_BTQ  25231360u    // 256*768 bf16
#define OFF_BTK  25624576u
#define OFF_BEFF 26017792u    // 2*256 f32
#define OFF_WVT  26019840u    // 256*256 bf16
#define OFF_WOT  26150912u    // 256*256 bf16
#define OFF_QB   26413056u    // 16384*256 bf16
#define OFF_KB   34801664u
#define OFF_VV   43190272u
#define OFF_CTX  51578880u

// ---------------- weight prep (folded conv mats, transposes, biases, zero-page) ----------------
__global__ __launch_bounds__(256) void prep(
    const float* __restrict__ Wq, const float* __restrict__ Wk,
    const float* __restrict__ bq, const float* __restrict__ bk,
    const float* __restrict__ wp, const float* __restrict__ wv,
    const float* __restrict__ wa, const float* __restrict__ b_pos,
    const float* __restrict__ Wv, const float* __restrict__ Wo,
    unsigned short* __restrict__ BtQ, unsigned short* __restrict__ BtK,
    float* __restrict__ beff, unsigned short* __restrict__ WVT,
    unsigned short* __restrict__ WOT, float* __restrict__ zeropage)
{
    int bid = blockIdx.x;
    if (bid < 1536) {                       // folded conv mats (Q side pre-scaled)
        int idx = bid * 256 + threadIdx.x;  // 2*3*256*256
        int which = idx / 196608;
        int r = idx - which * 196608;
        int j = r >> 16;
        int rem = r & 65535;
        int n = rem >> 8;
        int d = rem & 255;
        const float* W = which ? Wk : Wq;
        float val = wp[d * 3 + j] * W[d * 256 + n]
                  + wv[d * 3 + j] * W[(256 + d) * 256 + n]
                  + wa[d * 3 + j] * W[(512 + d) * 256 + n];
        if (!which) val *= SCL;
        (which ? BtK : BtQ)[n * 768 + j * 256 + d] = f2bf(val);
    } else if (bid < 2048) {                // Wv / Wo transposes (bf16)
        int idx = (bid - 1536) * 256 + threadIdx.x;   // 2*65536
        int which = idx >> 16;
        int r = idx & 65535;
        int n = r >> 8, kk = r & 255;
        if (!which) WVT[n * 256 + kk] = f2bf(Wv[kk * 256 + n]);
        else        WOT[n * 256 + kk] = f2bf(Wo[kk * 256 + n]);
    } else if (bid < 2050) {                // effective biases
        int which = bid - 2048;
        int n = threadIdx.x;
        const float* W = which ? Wk : Wq;
        const float* bb = which ? bk : bq;
        float s = bb[n];
        for (int d = 0; d < 256; ++d) s = fmaf(b_pos[d], W[d * 256 + n], s);
        if (!which) s *= SCL;
        beff[which * 256 + n] = s;
    } else {                                // zero-page (64 floats)
        if (threadIdx.x < 64) zeropage[threadIdx.x] = 0.f;
    }
}

// ---------------- fp32-A tap-inner GEMM: 128M x 128N, c-block outer, taps inner ----------------
// TAPS=3 (Q/K im2col, KTOT=768): A halo tile = 130 rows (t0-1 .. t0+128) staged
// ONCE per 64-channel block; tap reads LDS at row+tap. B (128n x 64k bf16)
// double-buffered across taps. TAPS=1 (V, KTOT=256): plain 128-row tile.
// A LDS rows = 64 f32 (16 chunks), phys chunk p at row r = logical p^(r&15);
// B rows = 64 bf16 (8 chunks), phys p^(r&7). cvt_pk at fragment time (RNE).
template<int TAPS>
__device__ __forceinline__ void gemmf32(
    const float* __restrict__ A, const unsigned short* __restrict__ Bt,
    const float* __restrict__ bias, const float* __restrict__ zeropage,
    unsigned short* __restrict__ Out, float* Asf, unsigned short* Bs)
{
    constexpr int KTOT = TAPS * 256;
    constexpr int ROWS_A = (TAPS > 1) ? 130 : 128;
    constexpr int NCHUNK_A = ROWS_A * 16;           // 2080 / 2048
    const int tid = threadIdx.x;
    const int wid = tid >> 6, l = tid & 63;
    const int l31 = l & 31, h2 = l >> 5;
    const int wm = wid >> 1, wn = wid & 1;
    const int m0 = blockIdx.x * 128, n0 = blockIdx.y * 128;
    const int seq = m0 >> 9, t0 = m0 & 511;

    f32x16 acc[2][2] = {};

    auto stageA = [&](int cb) {
        const int c0 = cb * 64;
        #pragma unroll
        for (int q = 0; q < (NCHUNK_A + 255) / 256; ++q) {
            int cidx = q * 256 + tid;
            if (cidx < NCHUNK_A) {
                int row = cidx >> 4, cch = cidx & 15;
                int csrc = (cch ^ (row & 15)) * 4;   // float offset in 64-wide slice
                const float* asrc;
                if constexpr (TAPS > 1) {
                    int st = t0 + row - 1;
                    asrc = (st >= 0 && st < 512)
                         ? A + ((size_t)(seq * 512 + st) * 256 + c0 + csrc)
                         : zeropage + csrc;
                } else {
                    asrc = A + ((size_t)(m0 + row) * 256 + c0 + csrc);
                }
                gll16(asrc, Asf + (size_t)cidx * 4);
            }
        }
    };
    auto stageB = [&](int cb, int tap, int b) {
        const int kbase = tap * 256 + cb * 64;
        #pragma unroll
        for (int q = 0; q < 4; ++q) {
            int cidx = q * 256 + tid;
            int row = cidx >> 3, c = cidx & 7;
            gll16(Bt + (size_t)(n0 + row) * KTOT + kbase + ((c ^ (row & 7)) * 8),
                  Bs + b * 8192 + cidx * 8);
        }
    };
    auto compute = [&](int tap, int b) {
        const unsigned short* bs = Bs + b * 8192;
        #pragma unroll
        for (int ks = 0; ks < 4; ++ks) {
            const int c = ks * 2 + h2;              // logical 8-elem chunk 0..7
            bf16x8 af[2], bfr[2];
            #pragma unroll
            for (int mt = 0; mt < 2; ++mt) {
                int r = wm * 64 + mt * 32 + l31 + tap;   // physical halo row
                f32x4 f0 = *(const f32x4*)&Asf[r * 64 + (((2 * c) ^ (r & 15)) * 4)];
                f32x4 f1 = *(const f32x4*)&Asf[r * 64 + (((2 * c + 1) ^ (r & 15)) * 4)];
                i32x4 w = {cvtpk(f0[0], f0[1]), cvtpk(f0[2], f0[3]),
                           cvtpk(f1[0], f1[1]), cvtpk(f1[2], f1[3])};
                af[mt] = __builtin_bit_cast(bf16x8, w);
            }
            #pragma unroll
            for (int nt = 0; nt < 2; ++nt) {
                int rn = wn * 64 + nt * 32 + l31;
                bfr[nt] = *(const bf16x8*)&bs[rn * 64 + ((c ^ (rn & 7)) * 8)];
            }
            #pragma unroll
            for (int mt = 0; mt < 2; ++mt)
                #pragma unroll
                for (int nt = 0; nt < 2; ++nt)
                    acc[mt][nt] = __builtin_amdgcn_mfma_f32_32x32x16_bf16(af[mt], bfr[nt], acc[mt][nt], 0, 0, 0);
        }
    };

    int buf = 0;
    #pragma unroll
    for (int cb = 0; cb < 4; ++cb) {
        if (cb) __syncthreads();            // all reads of Asf / Bs done
        stageA(cb);
        stageB(cb, 0, buf);
        __syncthreads();                    // staging landed (vmcnt drain)
        #pragma unroll
        for (int tap = 0; tap < TAPS; ++tap) {
            if (tap + 1 < TAPS) stageB(cb, tap + 1, buf ^ 1);   // fly under compute
            compute(tap, buf);
            if (tap + 1 < TAPS) { __syncthreads(); buf ^= 1; }  // next B landed
        }
    }

    // epilogue: C/D 32x32 layout: col = lane&31, row = (reg&3) + 8*(reg>>2) + 4*(lane>>5)
    #pragma unroll
    for (int nt = 0; nt < 2; ++nt) {
        const int col = n0 + wn * 64 + nt * 32 + l31;
        const float bb = bias[col];
        #pragma unroll
        for (int mt = 0; mt < 2; ++mt) {
            #pragma unroll
            for (int r = 0; r < 16; ++r) {
                const int row = m0 + wm * 64 + mt * 32 + 4 * h2 + (r & 3) + 8 * (r >> 2);
                Out[(size_t)row * 256 + col] = f2bf(acc[mt][nt][r] + bb);
            }
        }
    }
}

// ---------------- bf16-A GEMM (outproj): 128M x 128N, BK=64 (R15 verbatim) ----------------
template<int KTOT, typename OutT>
__device__ __forceinline__ void gemm97(
    const unsigned short* __restrict__ A, const unsigned short* __restrict__ Bt,
    const float* __restrict__ bias, OutT* __restrict__ Out,
    unsigned short* As, unsigned short* Bs)
{
    const int tid = threadIdx.x;
    const int wid = tid >> 6, l = tid & 63;
    const int l31 = l & 31, h2 = l >> 5;
    const int wm = wid >> 1, wn = wid & 1;
    const int m0 = blockIdx.x * 128, n0 = blockIdx.y * 128;

    f32x16 acc[2][2] = {};

    for (int k0 = 0; k0 < KTOT; k0 += 64) {
        __syncthreads();
        #pragma unroll
        for (int q = 0; q < 4; ++q) {
            int cidx = q * 256 + tid;
            int row = cidx >> 3;
            int csrc = ((cidx & 7) ^ (row & 7)) * 8;
            gll16(A + (size_t)(m0 + row) * 256 + (k0 & 255) + csrc, As + (size_t)cidx * 8);
            gll16(Bt + (size_t)(n0 + row) * KTOT + k0 + csrc, Bs + (size_t)cidx * 8);
        }
        __syncthreads();
        #pragma unroll
        for (int ks = 0; ks < 4; ++ks) {
            bf16x8 af[2], bfr[2];
            #pragma unroll
            for (int mt = 0; mt < 2; ++mt) {
                int r = wm * 64 + mt * 32 + l31;
                af[mt] = *(const bf16x8*)&As[r * 64 + (((ks * 2 + h2) ^ (r & 7)) * 8)];
            }
            #pragma unroll
            for (int nt = 0; nt < 2; ++nt) {
                int rn = wn * 64 + nt * 32 + l31;
                bfr[nt] = *(const bf16x8*)&Bs[rn * 64 + (((ks * 2 + h2) ^ (rn & 7)) * 8)];
            }
            #pragma unroll
            for (int mt = 0; mt < 2; ++mt)
                #pragma unroll
                for (int nt = 0; nt < 2; ++nt)
                    acc[mt][nt] = __builtin_amdgcn_mfma_f32_32x32x16_bf16(af[mt], bfr[nt], acc[mt][nt], 0, 0, 0);
        }
    }

    #pragma unroll
    for (int nt = 0; nt < 2; ++nt) {
        const int col = n0 + wn * 64 + nt * 32 + l31;
        const float bb = bias[col];
        #pragma unroll
        for (int mt = 0; mt < 2; ++mt) {
            #pragma unroll
            for (int r = 0; r < 16; ++r) {
                const int row = m0 + wm * 64 + mt * 32 + 4 * h2 + (r & 3) + 8 * (r >> 2);
                float v = acc[mt][nt][r] + bb;
                if constexpr (sizeof(OutT) == 2) Out[(size_t)row * 256 + col] = (OutT)f2bf(v);
                else Out[(size_t)row * 256 + col] = v;
            }
        }
    }
}

// one launch: z=0 Q-proj, z=1 K-proj (fp32 im2col TAPS=3), z=2 V-proj (TAPS=1)
__global__ __launch_bounds__(256) void proj_fused(
    const float* __restrict__ query, const float* __restrict__ key,
    const float* __restrict__ value,
    const unsigned short* __restrict__ BTQ, const unsigned short* __restrict__ BTK,
    const unsigned short* __restrict__ WVT,
    const float* __restrict__ BEFF, const float* __restrict__ bv,
    const float* __restrict__ zeropage,
    unsigned short* __restrict__ QB, unsigned short* __restrict__ KB,
    unsigned short* __restrict__ VV)
{
    __shared__ alignas(16) float Asf[130 * 64];          // 33.3 KB halo tile
    __shared__ alignas(16) unsigned short Bs[2 * 8192];  // 32 KB (2 bufs)
    const int z = blockIdx.z;
    if (z == 0)      gemmf32<3>(query, BTQ, BEFF, zeropage, QB, Asf, Bs);
    else if (z == 1) gemmf32<3>(key, BTK, BEFF + 256, zeropage, KB, Asf, Bs);
    else             gemmf32<1>(value, WVT, bv, zeropage, VV, Asf, Bs);
}

__global__ __launch_bounds__(256) void outproj(
    const unsigned short* __restrict__ CTX, const unsigned short* __restrict__ WOT,
    const float* __restrict__ bo, float* __restrict__ Out)
{
    __shared__ alignas(16) unsigned short As[8192];
    __shared__ alignas(16) unsigned short Bs[8192];
    gemm97<256, float>(CTX, WOT, bo, Out, As, Bs);
}

// ---------------- q-inner fused attention: 1 block per (bn,h), 8 waves (R15 verbatim) ----------------
__global__ __launch_bounds__(512) void attn_mfma(const unsigned short* __restrict__ Qb,
                                                 const unsigned short* __restrict__ Kb,
                                                 const unsigned short* __restrict__ Vv,
                                                 const int* __restrict__ mask,
                                                 unsigned short* __restrict__ ctx) {
    __shared__ alignas(16) unsigned short Ks[2][128 * 32];   // chunk-xor (c ^ (row&3))
    __shared__ alignas(16) unsigned short VsT[2][32 * 136];  // [d][key], 17-chunk rows
    __shared__ float Mb[2][128];

    const int bnh = blockIdx.x;
    const int bn = bnh >> 3, h = bnh & 7;
    const int tid = threadIdx.x, wid = tid >> 6, l = tid & 63;
    const int g = l >> 4, r15 = l & 15;
    const unsigned short* Qg = Qb + (size_t)bn * 512 * 256 + h * 32;
    const unsigned short* Kg = Kb + (size_t)bn * 512 * 256 + h * 32;
    const unsigned short* Vg = Vv + (size_t)bn * 512 * 256 + h * 32;
    const int* mp = mask + bn * 512;
    const int srow = tid >> 2;                       // K staging row
    const int vkey = tid & 127, vd0 = (tid >> 7) * 8;

    auto stageK = [&](int k0, int b) {
        int csrc = (((tid & 3) ^ (srow & 3))) * 8;
        gll16(Kg + ((size_t)(k0 + srow)) * 256 + csrc, &Ks[b][wid * 512]);
    };

    // ---- prologue: Q direct to regs; K0, V0, Mb0 staged ----
    bf16x8 bq[4];
    #pragma unroll
    for (int qt = 0; qt < 4; ++qt)
        bq[qt] = *(const bf16x8*)(const void*)(Qg + ((size_t)(qt * 128 + wid * 16 + r15)) * 256 + g * 8);

    stageK(0, 0);
    {
        i32x4 vr = *(const i32x4*)(const void*)(Vg + (size_t)vkey * 256 + vd0);
        #pragma unroll
        for (int i = 0; i < 4; ++i) {
            unsigned u = (unsigned)vr[i];
            VsT[0][(vd0 + 2 * i) * 136 + vkey] = (unsigned short)(u & 0xffff);
            VsT[0][(vd0 + 2 * i + 1) * 136 + vkey] = (unsigned short)(u >> 16);
        }
        if (tid < 128) Mb[0][tid] = (mp[tid] != 0) ? -1e9f : 0.f;
    }
    __syncthreads();

    float mrun[4], lrun[4];
    f32x4 accO[4][2] = {};
    #pragma unroll
    for (int qt = 0; qt < 4; ++qt) { mrun[qt] = -1e30f; lrun[qt] = 0.f; }

    for (int kt = 0; kt < 4; ++kt) {
        const int cur = kt & 1, nxt = cur ^ 1;
        const int k0n = kt * 128 + 128;

        i32x4 vr;
        int mraw = 0;
        if (kt < 3) {
            stageK(k0n, nxt);
            vr = *(const i32x4*)(const void*)(Vg + ((size_t)(k0n + vkey)) * 256 + vd0);
            if (tid < 128) mraw = mp[k0n + tid];
        }

        bf16x8 av[2][4];
        #pragma unroll
        for (int mt = 0; mt < 2; ++mt)
            #pragma unroll
            for (int s = 0; s < 4; ++s)
                av[mt][s] = *(const bf16x8*)&VsT[cur][(mt * 16 + r15) * 136 + 32 * s + 8 * g];

        #pragma unroll
        for (int qt = 0; qt < 4; ++qt) {
            float p[8][4];
            float rmax = -3e38f;
            __builtin_amdgcn_s_setprio(1);
            #pragma unroll
            for (int t2 = 0; t2 < 8; ++t2) {
                const int base = 32 * (t2 >> 1) + 4 * (t2 & 1);
                const int arow = base + 8 * (r15 >> 2) + (r15 & 3);
                bf16x8 ak = *(const bf16x8*)&Ks[cur][arow * 32 + ((g ^ (arow & 3)) * 8)];
                f32x4 cin = *(const f32x4*)&Mb[cur][base + 8 * g];
                f32x4 st = __builtin_amdgcn_mfma_f32_16x16x32_bf16(ak, bq[qt], cin, 0, 0, 0);
                #pragma unroll
                for (int r = 0; r < 4; ++r) p[t2][r] = st[r];
                rmax = fmaxf(rmax, fmaxf(fmaxf(st[0], st[1]), fmaxf(st[2], st[3])));
            }
            __builtin_amdgcn_s_setprio(0);
            rmax = fmaxf(rmax, __shfl_xor(rmax, 16, 64));
            rmax = fmaxf(rmax, __shfl_xor(rmax, 32, 64));

            if (__ballot(rmax > mrun[qt])) {
                float mnew = fmaxf(mrun[qt], rmax);
                float fs = ex2(mrun[qt] - mnew);
                lrun[qt] *= fs;
                accO[qt][0] *= fs;
                accO[qt][1] *= fs;
                mrun[qt] = mnew;
            }
            float psum = 0.f;
            #pragma unroll
            for (int t2 = 0; t2 < 8; ++t2)
                #pragma unroll
                for (int r = 0; r < 4; ++r) {
                    float e = ex2(p[t2][r] - mrun[qt]);
                    p[t2][r] = e;
                    psum += e;
                }
            psum += __shfl_xor(psum, 16, 64);
            psum += __shfl_xor(psum, 32, 64);
            lrun[qt] += psum;

            bf16x8 pb[4];
            #pragma unroll
            for (int s = 0; s < 4; ++s) {
                i32x4 bi = {cvtpk(p[2 * s][0], p[2 * s][1]), cvtpk(p[2 * s][2], p[2 * s][3]),
                            cvtpk(p[2 * s + 1][0], p[2 * s + 1][1]), cvtpk(p[2 * s + 1][2], p[2 * s + 1][3])};
                pb[s] = __builtin_bit_cast(bf16x8, bi);
            }

            __builtin_amdgcn_s_setprio(1);
            #pragma unroll
            for (int mt = 0; mt < 2; ++mt)
                #pragma unroll
                for (int s = 0; s < 4; ++s)
                    accO[qt][mt] = __builtin_amdgcn_mfma_f32_16x16x32_bf16(av[mt][s], pb[s], accO[qt][mt], 0, 0, 0);
            __builtin_amdgcn_s_setprio(0);
        }

        if (kt < 3) {
            #pragma unroll
            for (int i = 0; i < 4; ++i) {
                unsigned u = (unsigned)vr[i];
                VsT[nxt][(vd0 + 2 * i) * 136 + vkey] = (unsigned short)(u & 0xffff);
                VsT[nxt][(vd0 + 2 * i + 1) * 136 + vkey] = (unsigned short)(u >> 16);
            }
            if (tid < 128) Mb[nxt][tid] = (mraw != 0) ? -1e9f : 0.f;
        }
        __syncthreads();
    }

    #pragma unroll
    for (int qt = 0; qt < 4; ++qt) {
        const float inv = 1.f / lrun[qt];
        const size_t orow = (size_t)bn * 512 + qt * 128 + wid * 16 + r15;
        #pragma unroll
        for (int mt = 0; mt < 2; ++mt) {
            ushort4 o;
            o.x = f2bf(accO[qt][mt][0] * inv);
            o.y = f2bf(accO[qt][mt][1] * inv);
            o.z = f2bf(accO[qt][mt][2] * inv);
            o.w = f2bf(accO[qt][mt][3] * inv);
            *(ushort4*)&ctx[orow * 256 + h * 32 + mt * 16 + 4 * g] = o;
        }
    }
}

extern "C" void kernel_launch(void* const* d_in, const int* in_sizes, int n_in,
                              void* d_out, int out_size, void* d_ws, size_t ws_size,
                              hipStream_t stream) {
    const float* query = (const float*)d_in[0];
    const float* key   = (const float*)d_in[1];
    const float* value = (const float*)d_in[2];
    const int*   kpm   = (const int*)d_in[3];
    const float* w_pos = (const float*)d_in[4];
    const float* b_pos = (const float*)d_in[5];
    const float* w_vel = (const float*)d_in[6];
    const float* w_acc = (const float*)d_in[7];
    const float* Wq    = (const float*)d_in[8];
    const float* bq    = (const float*)d_in[9];
    const float* Wk    = (const float*)d_in[10];
    const float* bk    = (const float*)d_in[11];
    const float* Wv    = (const float*)d_in[12];
    const float* bv    = (const float*)d_in[13];
    const float* Wo    = (const float*)d_in[14];
    const float* bo    = (const float*)d_in[15];

    unsigned char* w = (unsigned char*)d_ws;
    float*          ZP  = (float*)(w + OFF_ZERO);
    unsigned short* BTQ = (unsigned short*)(w + OFF_BTQ);
    unsigned short* BTK = (unsigned short*)(w + OFF_BTK);
    float*          BEFF= (float*)(w + OFF_BEFF);
    unsigned short* WVT = (unsigned short*)(w + OFF_WVT);
    unsigned short* WOT = (unsigned short*)(w + OFF_WOT);
    unsigned short* QB  = (unsigned short*)(w + OFF_QB);
    unsigned short* KB  = (unsigned short*)(w + OFF_KB);
    unsigned short* VV  = (unsigned short*)(w + OFF_VV);
    unsigned short* CTX = (unsigned short*)(w + OFF_CTX);

    prep<<<2051, 256, 0, stream>>>(Wq, Wk, bq, bk, w_pos, w_vel, w_acc, b_pos,
                                   Wv, Wo, BTQ, BTK, BEFF, WVT, WOT, ZP);

    proj_fused<<<dim3(128, 2, 3), 256, 0, stream>>>(query, key, value, BTQ, BTK, WVT,
                                                    BEFF, bv, ZP, QB, KB, VV);

    attn_mfma<<<256, 512, 0, stream>>>(QB, KB, VV, kpm, CTX);

    outproj<<<dim3(128, 2), 256, 0, stream>>>(CTX, WOT, bo, (float*)d_out);
}